// Round 2
// baseline (343.492 us; speedup 1.0000x reference)
//
#include <hip/hip_runtime.h>
#include <hip/hip_bf16.h>

// Problem constants (from reference)
#define N_NODES 50000
#define N_EDGES 800000
#define N_FEAT  64
#define UNITS   128
#define OUT_C   (2 * UNITS)   // 256

// ---------------------------------------------------------------------------
// Kernel 0: detect whether edge_index arrived as int64 or int32.
// If int64 (little-endian, values < 50000), every odd int32 word is 0.
// 64 threads read words 1,3,...,127; all-zero => int64. P(false positive)
// for random int32 in [0,50000) is (1/50000)^64 ~ 0.
// ---------------------------------------------------------------------------
__global__ void detect_idx_dtype(const void* __restrict__ ei_raw,
                                 int* __restrict__ flag)
{
    const int* p = (const int*)ei_raw;
    int v = p[2 * threadIdx.x + 1];
    unsigned long long b = __ballot(v == 0);
    if (threadIdx.x == 0) *flag = (b == ~0ull) ? 1 : 0;
}

// ---------------------------------------------------------------------------
// Kernel 1: edge scatter. One 64-lane wave per edge: lane i loads x[col][i],
// atomically adds into seg[row][i]; lane 0 bumps the degree counter.
// Index dtype resolved at runtime via *flag (wave-uniform branch).
// Indices clamped so a bad decode fails validation instead of faulting.
// ---------------------------------------------------------------------------
__global__ __launch_bounds__(256) void edge_scatter(
    const float* __restrict__ x,
    const void* __restrict__ ei_raw,    // [2][E] int64 or int32
    const int* __restrict__ flag,
    float* __restrict__ seg,            // [N][64]
    float* __restrict__ cnt)            // [N]
{
    int wave = (blockIdx.x * blockDim.x + threadIdx.x) >> 6;
    int lane = threadIdx.x & 63;
    if (wave >= N_EDGES) return;

    int row, col;
    if (*flag) {
        const long long* ei = (const long long*)ei_raw;
        row = (int)ei[wave];
        col = (int)ei[(long long)N_EDGES + wave];
    } else {
        const int* ei = (const int*)ei_raw;
        row = ei[wave];
        col = ei[N_EDGES + wave];
    }
    row = min(max(row, 0), N_NODES - 1);
    col = min(max(col, 0), N_NODES - 1);

    float v = x[(long long)col * N_FEAT + lane];
    atomicAdd(&seg[(long long)row * N_FEAT + lane], v);
    if (lane == 0) atomicAdd(&cnt[row], 1.0f);
}

// ---------------------------------------------------------------------------
// Kernel 2: fused mean-divide + dual GEMM [N,64]x[64,128] (neighbor & self)
// + concat + bias + relu.  Block = 256 threads, 16 rows per block.
// LDS: combined weights W[64][256] (cols 0..127 = neighs_kernel,
// 128..255 = self_kernel) = 64 KB, plus 16x64 mean tile and 16x64 x tile.
// Thread (cg = t&63, rg = t>>6) computes rows [rg*4, rg*4+4) x cols
// [cg*4, cg*4+4).  W read: ds_read_b128, contiguous 16B/lane.  Input read:
// wave-uniform address -> broadcast.
// ---------------------------------------------------------------------------
#define ROWS_PER_BLOCK 16

__global__ __launch_bounds__(256) void fused_mean_gemm(
    const float* __restrict__ seg,
    const float* __restrict__ cnt,
    const float* __restrict__ x,
    const float* __restrict__ wn,     // [64][128]
    const float* __restrict__ wsf,    // [64][128]
    const float* __restrict__ bias,   // [256]
    float* __restrict__ out)          // [N][256]
{
    __shared__ float W[N_FEAT * OUT_C];                 // 64 KB
    __shared__ float in_mean[ROWS_PER_BLOCK][N_FEAT];   // 4 KB
    __shared__ float in_x[ROWS_PER_BLOCK][N_FEAT];      // 4 KB

    const int t = threadIdx.x;
    const int row0 = blockIdx.x * ROWS_PER_BLOCK;

    // Stage weights: 16384 floats = 4096 float4, 16 per thread.
    for (int i = t; i < (N_FEAT * OUT_C) / 4; i += 256) {
        int fl = i * 4;
        int k = fl >> 8;          // / 256
        int u = fl & 255;
        float4 v;
        if (u < UNITS) v = *(const float4*)&wn[k * UNITS + u];
        else           v = *(const float4*)&wsf[k * UNITS + (u - UNITS)];
        *(float4*)&W[fl] = v;
    }

    // Stage input rows (mean = seg/max(cnt,1), and x).
    for (int i = t; i < (ROWS_PER_BLOCK * N_FEAT) / 4; i += 256) {
        int fl = i * 4;
        int r = fl >> 6;          // / 64
        int k = fl & 63;
        int grow = row0 + r;
        float4 xm = make_float4(0.f, 0.f, 0.f, 0.f);
        float4 xv = xm;
        if (grow < N_NODES) {
            float inv = 1.0f / fmaxf(cnt[grow], 1.0f);
            float4 s = *(const float4*)&seg[(long long)grow * N_FEAT + k];
            xm = make_float4(s.x * inv, s.y * inv, s.z * inv, s.w * inv);
            xv = *(const float4*)&x[(long long)grow * N_FEAT + k];
        }
        *(float4*)&in_mean[r][k] = xm;
        *(float4*)&in_x[r][k]    = xv;
    }
    __syncthreads();

    const int cg = t & 63;        // column group: cols [cg*4, cg*4+4)
    const int rg = t >> 6;        // row group (wave id): rows [rg*4, rg*4+4)
    const int c0 = cg * 4;
    // cols 0..127 consume the mean tile, 128..255 the x tile. c0 is a
    // multiple of 4 so a col-group never straddles the boundary.
    const float(*inp)[N_FEAT] = (c0 < UNITS) ? in_mean : in_x;

    float acc[4][4];
    #pragma unroll
    for (int r = 0; r < 4; ++r)
        #pragma unroll
        for (int c = 0; c < 4; ++c) acc[r][c] = 0.f;

    #pragma unroll 4
    for (int k = 0; k < N_FEAT; ++k) {
        float4 w = *(const float4*)&W[k * OUT_C + c0];
        #pragma unroll
        for (int r = 0; r < 4; ++r) {
            float a = inp[rg * 4 + r][k];
            acc[r][0] += a * w.x;
            acc[r][1] += a * w.y;
            acc[r][2] += a * w.z;
            acc[r][3] += a * w.w;
        }
    }

    float4 b = *(const float4*)&bias[c0];
    #pragma unroll
    for (int r = 0; r < 4; ++r) {
        int grow = row0 + rg * 4 + r;
        if (grow >= N_NODES) continue;
        float4 o;
        o.x = fmaxf(acc[r][0] + b.x, 0.f);
        o.y = fmaxf(acc[r][1] + b.y, 0.f);
        o.z = fmaxf(acc[r][2] + b.z, 0.f);
        o.w = fmaxf(acc[r][3] + b.w, 0.f);
        *(float4*)&out[(long long)grow * OUT_C + c0] = o;
    }
}

// ---------------------------------------------------------------------------
extern "C" void kernel_launch(void* const* d_in, const int* in_sizes, int n_in,
                              void* d_out, int out_size, void* d_ws, size_t ws_size,
                              hipStream_t stream) {
    const float* x    = (const float*)d_in[0];
    const void*  ei   = d_in[1];                 // int64 or int32 [2][E]
    const float* wn   = (const float*)d_in[2];
    const float* wsf  = (const float*)d_in[3];
    const float* bias = (const float*)d_in[4];
    float*       out  = (float*)d_out;

    // Workspace layout: seg_sum [N][64] f32, cnt [N] f32, flag int.
    float* seg  = (float*)d_ws;
    float* cnt  = seg + (size_t)N_NODES * N_FEAT;
    int*   flag = (int*)(cnt + N_NODES);
    size_t zero_bytes = ((size_t)N_NODES * N_FEAT + N_NODES) * sizeof(float);
    hipMemsetAsync(d_ws, 0, zero_bytes, stream);

    detect_idx_dtype<<<1, 64, 0, stream>>>(ei, flag);

    // Edge scatter: 1 wave per edge, 4 waves (256 threads) per block.
    int blocks_scatter = (N_EDGES + 3) / 4;
    edge_scatter<<<blocks_scatter, 256, 0, stream>>>(x, ei, flag, seg, cnt);

    // Fused mean + GEMMs + bias + relu.
    int blocks_gemm = (N_NODES + ROWS_PER_BLOCK - 1) / ROWS_PER_BLOCK;  // 3125
    fused_mean_gemm<<<blocks_gemm, 256, 0, stream>>>(seg, cnt, x, wn, wsf, bias, out);
}